// Round 8
// baseline (123.443 us; speedup 1.0000x reference)
//
#include <hip/hip_runtime.h>

#define T_ 1000
#define T4_ 250
#define B_ 64
#define V_ 1024
#define LMAX_ 64
#define NEGF (-1e30f)
#define LOG2E_ 1.4426950408889634f
#define LN2_ 0.6931471805599453f

__device__ __forceinline__ float ex2(float x) { return __builtin_amdgcn_exp2f(x); }
__device__ __forceinline__ float lg2(float x) { return __builtin_amdgcn_logf(x); }
__device__ __forceinline__ float rlane(float x, int l) {
    return __int_as_float(__builtin_amdgcn_readlane(__float_as_int(x), l));
}
#define FENCE_ __builtin_amdgcn_sched_barrier(0)

// Q4(u) ~= log2(1+u) on [0,2]; Newton interp at {0,.5,1,1.5,2}; |err| <= ~2e-3.
// Q4(0)=0, Q4(1)=1, Q4(2)=log2(3) exact by construction.
__device__ __forceinline__ float Q4(float u) {
    return u * (1.412361f + u * (-0.571582f + u * (0.187621f - 0.028400f * u)));
}

__global__ void prep_tgt_k(const int* __restrict__ targets,
                           const int* __restrict__ tlen,
                           int* __restrict__ tgt_full) {
    int b = threadIdx.x;
    if (b >= B_) return;
    int off = 0;
    for (int i = 0; i < b; ++i) off += tlen[i];
    int L = tlen[b];
    for (int l = 0; l < LMAX_; ++l)
        tgt_full[b * LMAX_ + l] = (l < L) ? targets[off + l] : 0;
}

// em4[((b*250+t4)*64+lane)*4 + (t&3)] = log2e * lp[t, b, lane<63 ? tgt[lane] : BLANK]
__global__ __launch_bounds__(256) void gather_k(const float* __restrict__ lp,
                                                const int* __restrict__ tgt_full,
                                                const int* __restrict__ ilen,
                                                float* __restrict__ em4f) {
    int t4 = blockIdx.x % T4_;
    int b = blockIdx.x / T4_;
    int tl = threadIdx.x >> 6;
    int i = threadIdx.x & 63;
    int t = t4 * 4 + tl;
    if (t >= ilen[b]) return;
    int col = (i == 63) ? 0 : tgt_full[b * LMAX_ + i];
    const float* row = lp + (size_t)t * (B_ * V_) + (size_t)b * V_;
    em4f[(((size_t)b * T4_ + t4) * 64 + i) * 4 + tl] = row[col] * LOG2E_;
}

// One wave per sample. Lane i owns states 2i (blank) and 2i+1 (label i). L<=63.
__global__ __launch_bounds__(64) void ctc_rec_k(const float4* __restrict__ em4,
                                                const int* __restrict__ tgt_full,
                                                const int* __restrict__ ilen,
                                                const int* __restrict__ tlen,
                                                float* __restrict__ losses) {
    int b = blockIdx.x, lane = threadIdx.x;
    int L = tlen[b], Tin = ilen[b], Te = Tin - 1;
    int tg = tgt_full[b * LMAX_ + lane];
    int tgp = __shfl_up(tg, 1);
    bool skip1 = (lane >= 1) && (tg != 0) && (tg != tgp);
    bool is16 = (lane == 16), is32 = (lane == 32), is48 = (lane == 48);
    const float4* e4 = em4 + (size_t)b * (T4_ * 64) + lane;
    int Gc = Te >> 2;
    if (Gc < 0) Gc = 0;
    if (Gc > T4_ - 1) Gc = T4_ - 1;
    float a0 = NEGF, a1 = NEGF;

    auto ldE = [&](int g) -> float4 {
        int gm = g < Gc ? g : Gc;
        return e4[(size_t)gm * 64];
    };
    // p1m[lane] = x[lane-1], p1m[0] = NEGF. row_shr:1; lanes 0/16/32/48 are invalid
    // for row_shr so they take `old` = per-lane boundary value (readlane tree).
    auto shr1 = [&](float x) -> float {
        float v15 = rlane(x, 15), v31 = rlane(x, 31), v47 = rlane(x, 47);
        float bval = is16 ? v15 : (is32 ? v31 : (is48 ? v47 : NEGF));
        return __int_as_float(__builtin_amdgcn_update_dpp(
            __float_as_int(bval), __float_as_int(x), 0x111, 0xF, 0xF, false));
    };
    // even: na0 = lae(a0,p1m)+xb ; odd: na1 = lae3(a1,a0,sk)+xe, both via exp2+Q4,
    // odd computed as an independent parallel 3-way (no dependence on the even lae).
    auto step = [&](float xb, float xe) {
        float p1m = shr1(a1);
        float sk = skip1 ? p1m : NEGF;
        float m0 = fmaxf(a0, p1m);
        float u0 = ex2(fminf(a0, p1m) - m0);
        float na0 = (m0 + xb) + Q4(u0);
        float m1 = fmaxf(fmaxf(a1, a0), sk);
        float s = ex2(a1 - m1) + ex2(a0 - m1) + ex2(sk - m1);
        float na1 = (m1 + xe) + Q4(s - 1.0f);
        a0 = na0; a1 = na1;
    };

    if (Te >= 35) {
        float4 S0 = ldE(0), S1 = ldE(1), S2 = ldE(2), S3 = ldE(3);
        float4 S4 = ldE(4), S5 = ldE(5), S6 = ldE(6), S7 = ldE(7);
        FENCE_;
        a0 = (lane == 0) ? rlane(S0.x, 63) : NEGF;
        a1 = (lane == 0 && L > 0) ? S0.x : NEGF;
        step(rlane(S0.y, 63), S0.y); step(rlane(S0.z, 63), S0.z); step(rlane(S0.w, 63), S0.w);
        S0 = ldE(8);
        FENCE_;
#define SUBF(S, G) do {                                                        \
        float xb0_ = rlane(S.x, 63), xb1_ = rlane(S.y, 63);                    \
        float xb2_ = rlane(S.z, 63), xb3_ = rlane(S.w, 63);                    \
        step(xb0_, S.x); step(xb1_, S.y); step(xb2_, S.z); step(xb3_, S.w);    \
        S = ldE((G) + 8);                                                      \
        FENCE_;                                                                \
    } while (0)
        SUBF(S1, 1); SUBF(S2, 2); SUBF(S3, 3); SUBF(S4, 4);
        SUBF(S5, 5); SUBF(S6, 6); SUBF(S7, 7);
        int c = 1;
        for (; 32 * c + 31 <= Te; ++c) {
            int g0 = 8 * c;
            SUBF(S0, g0 + 0); SUBF(S1, g0 + 1); SUBF(S2, g0 + 2); SUBF(S3, g0 + 3);
            SUBF(S4, g0 + 4); SUBF(S5, g0 + 5); SUBF(S6, g0 + 6); SUBF(S7, g0 + 7);
        }
#undef SUBF
        int tb = 32 * c;
#define SUBT(S, T0) do {                                                       \
        float xb0_ = rlane(S.x, 63), xb1_ = rlane(S.y, 63);                    \
        float xb2_ = rlane(S.z, 63), xb3_ = rlane(S.w, 63);                    \
        if ((T0) + 0 <= Te) step(xb0_, S.x);                                   \
        if ((T0) + 1 <= Te) step(xb1_, S.y);                                   \
        if ((T0) + 2 <= Te) step(xb2_, S.z);                                   \
        if ((T0) + 3 <= Te) step(xb3_, S.w);                                   \
    } while (0)
        SUBT(S0, tb + 0);  SUBT(S1, tb + 4);  SUBT(S2, tb + 8);  SUBT(S3, tb + 12);
        SUBT(S4, tb + 16); SUBT(S5, tb + 20); SUBT(S6, tb + 24); SUBT(S7, tb + 28);
#undef SUBT
    } else {
        // small-Te safety path (never hit: Tin >= 500)
        float4 E0 = e4[0];
        a0 = (lane == 0) ? rlane(E0.x, 63) : NEGF;
        a1 = (lane == 0 && L > 0) ? E0.x : NEGF;
        for (int g = 0; 4 * g <= Te; ++g) {
            int gm = g < Gc ? g : Gc;
            float4 E = e4[(size_t)gm * 64];
            if (4 * g + 0 <= Te && 4 * g + 0 >= 1) step(rlane(E.x, 63), E.x);
            if (4 * g + 1 <= Te && 4 * g + 1 >= 1) step(rlane(E.y, 63), E.y);
            if (4 * g + 2 <= Te && 4 * g + 2 >= 1) step(rlane(E.z, 63), E.z);
            if (4 * g + 3 <= Te && 4 * g + 3 >= 1) step(rlane(E.w, 63), E.w);
        }
    }

    // end_ll at t = Tin-1 (log2 domain, exact lae once)
    int lidx = (L > 0) ? (L - 1) : 0;
    float aPrev = __shfl(a1, lidx);
    float aLast = __shfl(a0, (L < 63) ? L : 63);   // state 2L (blank), L<=63
    float x = aLast, y = (L > 0) ? aPrev : NEGF;
    float m = fmaxf(x, y), d = fminf(x, y) - m;
    float fin = m + lg2(1.0f + ex2(d));
    if (Tin <= 0) fin = NEGF;
    if (lane == 0) {
        float loss = (L > 0) ? -fin * LN2_ : 0.0f;
        if (!(loss < 1e29f)) loss = 0.0f;          // zero_infinity (NaN-safe)
        losses[b] = loss;
    }
}

// Fallback when ws too small: per-step scattered loads (slow, correct).
__global__ __launch_bounds__(64) void ctc_rec_direct_k(const float* __restrict__ lp,
                                                       const int* __restrict__ tgt_full,
                                                       const int* __restrict__ ilen,
                                                       const int* __restrict__ tlen,
                                                       float* __restrict__ losses) {
    int b = blockIdx.x, lane = threadIdx.x;
    int L = tlen[b], Tin = ilen[b], Te = Tin - 1;
    int tg = tgt_full[b * LMAX_ + lane];
    int tgp = __shfl_up(tg, 1);
    bool skip1 = (lane >= 1) && (tg != 0) && (tg != tgp);
    bool is16 = (lane == 16), is32 = (lane == 32), is48 = (lane == 48);
    int col = (lane == 63) ? 0 : tg;
    const float* src = lp + (size_t)b * V_;
    const long long stride = (long long)B_ * V_;
    float a0 = NEGF, a1 = NEGF;
    auto shr1 = [&](float x) -> float {
        float v15 = rlane(x, 15), v31 = rlane(x, 31), v47 = rlane(x, 47);
        float bval = is16 ? v15 : (is32 ? v31 : (is48 ? v47 : NEGF));
        return __int_as_float(__builtin_amdgcn_update_dpp(
            __float_as_int(bval), __float_as_int(x), 0x111, 0xF, 0xF, false));
    };
    auto step = [&](float xb, float xe) {
        float p1m = shr1(a1);
        float sk = skip1 ? p1m : NEGF;
        float m0 = fmaxf(a0, p1m);
        float u0 = ex2(fminf(a0, p1m) - m0);
        float na0 = (m0 + xb) + Q4(u0);
        float m1 = fmaxf(fmaxf(a1, a0), sk);
        float s = ex2(a1 - m1) + ex2(a0 - m1) + ex2(sk - m1);
        float na1 = (m1 + xe) + Q4(s - 1.0f);
        a0 = na0; a1 = na1;
    };
    if (Tin >= 1) {
        float e = src[col] * LOG2E_;
        a0 = (lane == 0) ? rlane(e, 63) : NEGF;
        a1 = (lane == 0 && L > 0) ? e : NEGF;
        for (int t = 1; t <= Te; ++t) {
            float xe = src[(long long)t * stride + col] * LOG2E_;
            step(rlane(xe, 63), xe);
        }
    }
    int lidx = (L > 0) ? (L - 1) : 0;
    float aPrev = __shfl(a1, lidx);
    float aLast = __shfl(a0, (L < 63) ? L : 63);
    float x = aLast, y = (L > 0) ? aPrev : NEGF;
    float m = fmaxf(x, y), d = fminf(x, y) - m;
    float fin = m + lg2(1.0f + ex2(d));
    if (Tin <= 0) fin = NEGF;
    if (lane == 0) {
        float loss = (L > 0) ? -fin * LN2_ : 0.0f;
        if (!(loss < 1e29f)) loss = 0.0f;
        losses[b] = loss;
    }
}

__global__ __launch_bounds__(64) void finalize_k(const float* __restrict__ losses,
                                                 const int* __restrict__ gid,
                                                 float* __restrict__ out) {
    int lane = threadIdx.x;
    float l = losses[lane];
    int g = gid[lane];
    float s = l;
    float s0 = (g == 0) ? l : 0.0f, c0 = (g == 0) ? 1.0f : 0.0f;
    float s1 = (g == 1) ? l : 0.0f, c1 = (g == 1) ? 1.0f : 0.0f;
    for (int off = 32; off; off >>= 1) {
        s  += __shfl_xor(s, off);
        s0 += __shfl_xor(s0, off);
        c0 += __shfl_xor(c0, off);
        s1 += __shfl_xor(s1, off);
        c1 += __shfl_xor(c1, off);
    }
    if (lane == 0) {
        float base = s * (1.0f / B_);
        float m0 = s0 / fmaxf(c0, 1.0f);
        float m1 = s1 / fmaxf(c1, 1.0f);
        float mean = 0.5f * (m0 + m1);
        float var = (m0 - mean) * (m0 - mean) + (m1 - mean) * (m1 - mean); // ddof=1, N=2
        out[0] = base + 0.5f * var;
        out[1] = base;
        out[2] = var;
    }
}

extern "C" void kernel_launch(void* const* d_in, const int* in_sizes, int n_in,
                              void* d_out, int out_size, void* d_ws, size_t ws_size,
                              hipStream_t stream) {
    const float* lp = (const float*)d_in[0];
    const int* targets = (const int*)d_in[1];
    const int* ilen = (const int*)d_in[2];
    const int* tlen = (const int*)d_in[3];
    const int* gid = (const int*)d_in[4];
    float* out = (float*)d_out;

    char* ws = (char*)d_ws;
    int* tgt_full = (int*)ws;                         // 16 KB
    float* losses = (float*)(ws + 16384);             // 256 B
    float* em4f = (float*)(ws + 32768);               // 64*250*64*16 B = 16.38 MB
    size_t need = 32768 + (size_t)B_ * T4_ * 64 * 16;

    prep_tgt_k<<<1, 64, 0, stream>>>(targets, tlen, tgt_full);
    if (ws_size >= need) {
        gather_k<<<B_ * T4_, 256, 0, stream>>>(lp, tgt_full, ilen, em4f);
        ctc_rec_k<<<B_, 64, 0, stream>>>((const float4*)em4f, tgt_full, ilen, tlen, losses);
    } else {
        ctc_rec_direct_k<<<B_, 64, 0, stream>>>(lp, tgt_full, ilen, tlen, losses);
    }
    finalize_k<<<1, 64, 0, stream>>>(losses, gid, out);
}

// Round 9
// 92.187 us; speedup vs baseline: 1.3391x; 1.3391x over previous
//
#include <hip/hip_runtime.h>

#define T_ 1000
#define B_ 64
#define V_ 1024
#define LMAX_ 64
#define NEGF (-1e30f)
#define LOG2E_ 1.4426950408889634f
#define LN2_ 0.6931471805599453f
// Q3(u) ~= log2(1+u), u in [0,1]; Q3(1)=1 exact; |err| <= ~3e-3
#define P0C 1.4405f
#define P1C (-0.64178f)
#define P2C 0.20128f

__device__ __forceinline__ float ex2(float x) { return __builtin_amdgcn_exp2f(x); }
__device__ __forceinline__ float lg2(float x) { return __builtin_amdgcn_logf(x); }
__device__ __forceinline__ float rlane(float x, int l) {
    return __int_as_float(__builtin_amdgcn_readlane(__float_as_int(x), l));
}
#define FENCE_ __builtin_amdgcn_sched_barrier(0)

__global__ void prep_tgt_k(const int* __restrict__ targets,
                           const int* __restrict__ tlen,
                           int* __restrict__ tgt_full) {
    int b = threadIdx.x;
    if (b >= B_) return;
    int off = 0;
    for (int i = 0; i < b; ++i) off += tlen[i];
    int L = tlen[b];
    for (int l = 0; l < LMAX_; ++l)
        tgt_full[b * LMAX_ + l] = (l < L) ? targets[off + l] : 0;
}

// One wave per sample, fused gather+recursion. Lane i owns states 2i (blank)
// and 2i+1 (label i); lane 63's label slot carries the BLANK column (L<=63).
// Loads come straight from lp: uniform base (lp + t*B*V) + per-lane voffset.
__global__ __launch_bounds__(64) void ctc_rec_k(const float* __restrict__ lp,
                                                const int* __restrict__ tgt_full,
                                                const int* __restrict__ ilen,
                                                const int* __restrict__ tlen,
                                                float* __restrict__ losses) {
    int b = blockIdx.x, lane = threadIdx.x;
    int L = tlen[b], Tin = ilen[b], Te = Tin - 1;
    int tg = tgt_full[b * LMAX_ + lane];
    int tgp = __shfl_up(tg, 1);
    bool skip1 = (lane >= 1) && (tg != 0) && (tg != tgp);
    bool is16 = (lane == 16), is32 = (lane == 32), is48 = (lane == 48);
    int col = (lane == 63) ? 0 : tg;
    int idx = b * V_ + col;                       // per-lane element offset within a t-slab
    float a0 = NEGF, a1 = NEGF;

    // raw (unscaled) loads of 4 consecutive timesteps, each clamped to Te.
    auto ldG = [&](int g, float4& S) {
        int t0 = 4 * g;
        int ta = t0 < Te ? t0 : Te;
        int tb = t0 + 1 < Te ? t0 + 1 : Te;
        int tc = t0 + 2 < Te ? t0 + 2 : Te;
        int td = t0 + 3 < Te ? t0 + 3 : Te;
        S.x = (lp + ((size_t)ta << 16))[idx];     // t-stride = B_*V_ = 65536 floats
        S.y = (lp + ((size_t)tb << 16))[idx];
        S.z = (lp + ((size_t)tc << 16))[idx];
        S.w = (lp + ((size_t)td << 16))[idx];
    };
    // p1m[lane] = x[lane-1], p1m[0] = NEGF: row_shr:1 with per-lane boundary
    // value folded into DPP `old` (lanes 0/16/32/48 are invalid for row_shr).
    auto shr1 = [&](float x) -> float {
        float v15 = rlane(x, 15), v31 = rlane(x, 31), v47 = rlane(x, 47);
        float bval = is16 ? v15 : (is32 ? v31 : (is48 ? v47 : NEGF));
        return __int_as_float(__builtin_amdgcn_update_dpp(
            __float_as_int(bval), __float_as_int(x), 0x111, 0xF, 0xF, false));
    };
    // even: na0 = lae(a0,p1m)+xb ; odd: na1 = lae(a1, skip?U:a0)+xe  (U shared).
    // lae(x,y) = max + Q3(exp2(-|x-y|)); -|.| via free source modifiers.
    auto step = [&](float xb, float xe) {
        float p1m = shr1(a1);
        float d0 = a0 - p1m;
        float m0 = fmaxf(a0, p1m);
        float u = ex2(-fabsf(d0));
        float h = fmaf(u, P2C, P1C);
        h = fmaf(u, h, P0C);
        float U = fmaf(u, h, m0);                 // lae(a0, p1m)
        float na0 = U + xb;
        float w = skip1 ? U : a0;
        float d1 = a1 - w;
        float m1 = fmaxf(a1, w);
        float v = ex2(-fabsf(d1));
        float h1 = fmaf(v, P2C, P1C);
        h1 = fmaf(v, h1, P0C);
        float mxe = m1 + xe;
        float na1 = fmaf(v, h1, mxe);
        a0 = na0; a1 = na1;
    };

    if (Te >= 35) {
        float4 S0, S1, S2, S3, S4, S5, S6, S7;
        ldG(0, S0); ldG(1, S1); ldG(2, S2); ldG(3, S3);
        ldG(4, S4); ldG(5, S5); ldG(6, S6); ldG(7, S7);
        FENCE_;
        {   // group 0: t=0 init + steps t=1..3 (Te>=35 so unguarded)
            float e0 = S0.x * LOG2E_, e1 = S0.y * LOG2E_;
            float e2 = S0.z * LOG2E_, e3 = S0.w * LOG2E_;
            a0 = (lane == 0) ? rlane(e0, 63) : NEGF;
            a1 = (lane == 0 && L > 0) ? e0 : NEGF;
            step(rlane(e1, 63), e1); step(rlane(e2, 63), e2); step(rlane(e3, 63), e3);
            ldG(8, S0);
            FENCE_;
        }
#define SUBF(S, G) do {                                                        \
        float e0_ = S.x * LOG2E_, e1_ = S.y * LOG2E_;                          \
        float e2_ = S.z * LOG2E_, e3_ = S.w * LOG2E_;                          \
        float b0_ = rlane(e0_, 63), b1_ = rlane(e1_, 63);                      \
        float b2_ = rlane(e2_, 63), b3_ = rlane(e3_, 63);                      \
        step(b0_, e0_); step(b1_, e1_); step(b2_, e2_); step(b3_, e3_);        \
        ldG((G) + 8, S);                                                       \
        FENCE_;                                                                \
    } while (0)
        SUBF(S1, 1); SUBF(S2, 2); SUBF(S3, 3); SUBF(S4, 4);
        SUBF(S5, 5); SUBF(S6, 6); SUBF(S7, 7);
        int c = 1;
        for (; 32 * c + 31 <= Te; ++c) {
            int g0 = 8 * c;
            SUBF(S0, g0 + 0); SUBF(S1, g0 + 1); SUBF(S2, g0 + 2); SUBF(S3, g0 + 3);
            SUBF(S4, g0 + 4); SUBF(S5, g0 + 5); SUBF(S6, g0 + 6); SUBF(S7, g0 + 7);
        }
#undef SUBF
        int tb = 32 * c;
#define SUBT(S, T0) do {                                                       \
        float e0_ = S.x * LOG2E_, e1_ = S.y * LOG2E_;                          \
        float e2_ = S.z * LOG2E_, e3_ = S.w * LOG2E_;                          \
        float b0_ = rlane(e0_, 63), b1_ = rlane(e1_, 63);                      \
        float b2_ = rlane(e2_, 63), b3_ = rlane(e3_, 63);                      \
        if ((T0) + 0 <= Te) step(b0_, e0_);                                    \
        if ((T0) + 1 <= Te) step(b1_, e1_);                                    \
        if ((T0) + 2 <= Te) step(b2_, e2_);                                    \
        if ((T0) + 3 <= Te) step(b3_, e3_);                                    \
    } while (0)
        SUBT(S0, tb + 0);  SUBT(S1, tb + 4);  SUBT(S2, tb + 8);  SUBT(S3, tb + 12);
        SUBT(S4, tb + 16); SUBT(S5, tb + 20); SUBT(S6, tb + 24); SUBT(S7, tb + 28);
#undef SUBT
    } else {
        // small-Te safety path (never hit: Tin >= 500)
        float e = (lp)[idx] * LOG2E_;
        a0 = (lane == 0) ? rlane(e, 63) : NEGF;
        a1 = (lane == 0 && L > 0) ? e : NEGF;
        for (int t = 1; t <= Te; ++t) {
            float xe = (lp + ((size_t)t << 16))[idx] * LOG2E_;
            step(rlane(xe, 63), xe);
        }
    }

    // end_ll at t = Tin-1 (log2 domain, exact lae once)
    int lidx = (L > 0) ? (L - 1) : 0;
    float aPrev = __shfl(a1, lidx);
    float aLast = __shfl(a0, (L < 63) ? L : 63);   // state 2L (blank), L<=63
    float x = aLast, y = (L > 0) ? aPrev : NEGF;
    float m = fmaxf(x, y), d = fminf(x, y) - m;
    float fin = m + lg2(1.0f + ex2(d));
    if (Tin <= 0) fin = NEGF;
    if (lane == 0) {
        float loss = (L > 0) ? -fin * LN2_ : 0.0f;
        if (!(loss < 1e29f)) loss = 0.0f;          // zero_infinity (NaN-safe)
        losses[b] = loss;
    }
}

__global__ __launch_bounds__(64) void finalize_k(const float* __restrict__ losses,
                                                 const int* __restrict__ gid,
                                                 float* __restrict__ out) {
    int lane = threadIdx.x;
    float l = losses[lane];
    int g = gid[lane];
    float s = l;
    float s0 = (g == 0) ? l : 0.0f, c0 = (g == 0) ? 1.0f : 0.0f;
    float s1 = (g == 1) ? l : 0.0f, c1 = (g == 1) ? 1.0f : 0.0f;
    for (int off = 32; off; off >>= 1) {
        s  += __shfl_xor(s, off);
        s0 += __shfl_xor(s0, off);
        c0 += __shfl_xor(c0, off);
        s1 += __shfl_xor(s1, off);
        c1 += __shfl_xor(c1, off);
    }
    if (lane == 0) {
        float base = s * (1.0f / B_);
        float m0 = s0 / fmaxf(c0, 1.0f);
        float m1 = s1 / fmaxf(c1, 1.0f);
        float mean = 0.5f * (m0 + m1);
        float var = (m0 - mean) * (m0 - mean) + (m1 - mean) * (m1 - mean); // ddof=1, N=2
        out[0] = base + 0.5f * var;
        out[1] = base;
        out[2] = var;
    }
}

extern "C" void kernel_launch(void* const* d_in, const int* in_sizes, int n_in,
                              void* d_out, int out_size, void* d_ws, size_t ws_size,
                              hipStream_t stream) {
    const float* lp = (const float*)d_in[0];
    const int* targets = (const int*)d_in[1];
    const int* ilen = (const int*)d_in[2];
    const int* tlen = (const int*)d_in[3];
    const int* gid = (const int*)d_in[4];
    float* out = (float*)d_out;

    char* ws = (char*)d_ws;
    int* tgt_full = (int*)ws;                         // 16 KB
    float* losses = (float*)(ws + 16384);             // 256 B

    prep_tgt_k<<<1, 64, 0, stream>>>(targets, tlen, tgt_full);
    ctc_rec_k<<<B_, 64, 0, stream>>>(lp, tgt_full, ilen, tlen, losses);
    finalize_k<<<1, 64, 0, stream>>>(losses, gid, out);
}

// Round 10
// 46.366 us; speedup vs baseline: 2.6624x; 1.9882x over previous
//
#include <hip/hip_runtime.h>

#define T_ 1000
#define B_ 64
#define V_ 1024
#define LMAX_ 64
#define NEGF (-1e30f)
#define LOG2E_ 1.4426950408889634f
#define LN2_ 0.6931471805599453f
// Q3(u) ~= log2(1+u), u in [0,1]; Q3(1)=1 exact; |err| <= ~3e-3
#define P0C 1.4405f
#define P1C (-0.64178f)
#define P2C 0.20128f

__device__ __forceinline__ float ex2(float x) { return __builtin_amdgcn_exp2f(x); }
__device__ __forceinline__ float lg2(float x) { return __builtin_amdgcn_logf(x); }
__device__ __forceinline__ float rlane(float x, int l) {
    return __int_as_float(__builtin_amdgcn_readlane(__float_as_int(x), l));
}
#define FENCE_ __builtin_amdgcn_sched_barrier(0)

// In-wave target setup (B_ == 64 == wave): lane l gets tgt[l] of sample b, plus L.
__device__ __forceinline__ void load_tgt(const int* __restrict__ targets,
                                         const int* __restrict__ tlen,
                                         int b, int lane, int& tg, int& L) {
    int tl = tlen[lane];
    L = __shfl(tl, b);
    int v = (lane < b) ? tl : 0;
    for (int off = 32; off; off >>= 1) v += __shfl_xor(v, off);  // offset_b (uniform)
    tg = (lane < L) ? targets[v + lane] : 0;
}

// Fused fwd/bwd CTC. Blocks 0..63: forward alpha to t=M (M=Te/2).
// Blocks 64..127: backward beta from Te down to M (consuming em at t=Te..M+1).
// Lane i owns states 2i (blank) / 2i+1 (label i); lane 63's label slot = BLANK col (L<=63).
// Junction states written to aw[b][4][64] = {a0,a1,B0,B1}.
__global__ __launch_bounds__(64) void ctc_fb_k(const float* __restrict__ lp,
                                               const int* __restrict__ targets,
                                               const int* __restrict__ tlen,
                                               const int* __restrict__ ilen,
                                               float* __restrict__ aw) {
    int blk = blockIdx.x, lane = threadIdx.x;
    bool isFwd = blk < B_;
    int b = isFwd ? blk : blk - B_;
    int tg, L;
    load_tgt(targets, tlen, b, lane, tg, L);
    int Tin = ilen[b], Te = Tin - 1;
    int M = Te >> 1;
    int tgp = __shfl_up(tg, 1);
    bool skip1 = (lane >= 1) && (tg != 0) && (tg != tgp);
    int col = (lane == 63) ? 0 : tg;
    int idx = (b << 10) + col;                    // element offset within a t-slab
    float* awb = aw + b * 256;

    if (isFwd) {
        bool is16 = (lane == 16), is32 = (lane == 32), is48 = (lane == 48);
        float a0 = NEGF, a1 = NEGF;
        auto ldG = [&](int g, float4& S) {        // t ascending, clamped to M
            int t0 = 4 * g;
            int ta = t0 < M ? t0 : M, tb2 = t0 + 1 < M ? t0 + 1 : M;
            int tc = t0 + 2 < M ? t0 + 2 : M, td = t0 + 3 < M ? t0 + 3 : M;
            S.x = (lp + ((size_t)ta << 16))[idx];
            S.y = (lp + ((size_t)tb2 << 16))[idx];
            S.z = (lp + ((size_t)tc << 16))[idx];
            S.w = (lp + ((size_t)td << 16))[idx];
        };
        auto shr1 = [&](float x) -> float {       // lane i <- x[i-1]; lane 0 <- NEGF
            float v15 = rlane(x, 15), v31 = rlane(x, 31), v47 = rlane(x, 47);
            float bval = is16 ? v15 : (is32 ? v31 : (is48 ? v47 : NEGF));
            return __int_as_float(__builtin_amdgcn_update_dpp(
                __float_as_int(bval), __float_as_int(x), 0x111, 0xF, 0xF, false));
        };
        auto step = [&](float xb, float xe) {
            float p1m = shr1(a1);
            float d0 = a0 - p1m;
            float m0 = fmaxf(a0, p1m);
            float u = ex2(-fabsf(d0));
            float h = fmaf(u, P2C, P1C);
            h = fmaf(u, h, P0C);
            float U = fmaf(u, h, m0);             // lae(a0, p1m)
            float na0 = U + xb;
            float w = skip1 ? U : a0;
            float d1 = a1 - w;
            float m1 = fmaxf(a1, w);
            float v = ex2(-fabsf(d1));
            float h1 = fmaf(v, P2C, P1C);
            h1 = fmaf(v, h1, P0C);
            float na1 = fmaf(v, h1, m1 + xe);
            a0 = na0; a1 = na1;
        };
        if (M >= 35) {
            float4 S0, S1, S2, S3, S4, S5, S6, S7;
            ldG(0, S0); ldG(1, S1); ldG(2, S2); ldG(3, S3);
            ldG(4, S4); ldG(5, S5); ldG(6, S6); ldG(7, S7);
            FENCE_;
            {
                float e0 = S0.x * LOG2E_, e1 = S0.y * LOG2E_;
                float e2 = S0.z * LOG2E_, e3 = S0.w * LOG2E_;
                a0 = (lane == 0) ? rlane(e0, 63) : NEGF;
                a1 = (lane == 0 && L > 0) ? e0 : NEGF;
                step(rlane(e1, 63), e1); step(rlane(e2, 63), e2); step(rlane(e3, 63), e3);
                ldG(8, S0);
                FENCE_;
            }
#define SUBF_F(S, G) do {                                                      \
            float e0_ = S.x * LOG2E_, e1_ = S.y * LOG2E_;                      \
            float e2_ = S.z * LOG2E_, e3_ = S.w * LOG2E_;                      \
            float b0_ = rlane(e0_, 63), b1_ = rlane(e1_, 63);                  \
            float b2_ = rlane(e2_, 63), b3_ = rlane(e3_, 63);                  \
            step(b0_, e0_); step(b1_, e1_); step(b2_, e2_); step(b3_, e3_);    \
            ldG((G) + 8, S);                                                   \
            FENCE_;                                                            \
        } while (0)
            SUBF_F(S1, 1); SUBF_F(S2, 2); SUBF_F(S3, 3); SUBF_F(S4, 4);
            SUBF_F(S5, 5); SUBF_F(S6, 6); SUBF_F(S7, 7);
            int c = 1;
            for (; 32 * c + 31 <= M; ++c) {
                int g0 = 8 * c;
                SUBF_F(S0, g0 + 0); SUBF_F(S1, g0 + 1); SUBF_F(S2, g0 + 2); SUBF_F(S3, g0 + 3);
                SUBF_F(S4, g0 + 4); SUBF_F(S5, g0 + 5); SUBF_F(S6, g0 + 6); SUBF_F(S7, g0 + 7);
            }
#undef SUBF_F
            int tb = 32 * c;
#define SUBT_F(S, T0) do {                                                     \
            float e0_ = S.x * LOG2E_, e1_ = S.y * LOG2E_;                      \
            float e2_ = S.z * LOG2E_, e3_ = S.w * LOG2E_;                      \
            float b0_ = rlane(e0_, 63), b1_ = rlane(e1_, 63);                  \
            float b2_ = rlane(e2_, 63), b3_ = rlane(e3_, 63);                  \
            if ((T0) + 0 <= M) step(b0_, e0_);                                 \
            if ((T0) + 1 <= M) step(b1_, e1_);                                 \
            if ((T0) + 2 <= M) step(b2_, e2_);                                 \
            if ((T0) + 3 <= M) step(b3_, e3_);                                 \
        } while (0)
            SUBT_F(S0, tb + 0);  SUBT_F(S1, tb + 4);  SUBT_F(S2, tb + 8);  SUBT_F(S3, tb + 12);
            SUBT_F(S4, tb + 16); SUBT_F(S5, tb + 20); SUBT_F(S6, tb + 24); SUBT_F(S7, tb + 28);
#undef SUBT_F
        } else {
            float e = lp[idx] * LOG2E_;
            a0 = (lane == 0) ? rlane(e, 63) : NEGF;
            a1 = (lane == 0 && L > 0) ? e : NEGF;
            for (int t = 1; t <= M; ++t) {
                float xe = (lp + ((size_t)t << 16))[idx] * LOG2E_;
                step(rlane(xe, 63), xe);
            }
        }
        awb[lane] = a0;
        awb[64 + lane] = a1;
    } else {
        // ---------------- backward ----------------
        bool is15 = (lane == 15), is31 = (lane == 31), is47 = (lane == 47);
        int K = Te - M;                            // steps; em t = Te-k, k=0..K-1
        float B0 = (lane == L) ? 0.0f : NEGF;      // state 2L
        float B1 = (L > 0 && lane == L - 1) ? 0.0f : NEGF;  // state 2L-1
        auto ldG = [&](int g, float4& S) {         // t descending, clamped to 0
            int t0 = Te - 4 * g;
            int ta = t0 > 0 ? t0 : 0, tb2 = t0 - 1 > 0 ? t0 - 1 : 0;
            int tc = t0 - 2 > 0 ? t0 - 2 : 0, td = t0 - 3 > 0 ? t0 - 3 : 0;
            S.x = (lp + ((size_t)ta << 16))[idx];
            S.y = (lp + ((size_t)tb2 << 16))[idx];
            S.z = (lp + ((size_t)tc << 16))[idx];
            S.w = (lp + ((size_t)td << 16))[idx];
        };
        auto shl1 = [&](float x) -> float {        // lane i <- x[i+1]; lane 63 <- NEGF
            float v16 = rlane(x, 16), v32 = rlane(x, 32), v48 = rlane(x, 48);
            float bval = is15 ? v16 : (is31 ? v32 : (is47 ? v48 : NEGF));
            return __int_as_float(__builtin_amdgcn_update_dpp(
                __float_as_int(bval), __float_as_int(x), 0x101, 0xF, 0xF, false));
        };
        // beta step (em at t+1): B0' = lae(xb+B0, xe+B1);
        // B1' = lae(xe+B1, shl1(skip1 ? B0'(has both succ terms) : xb+B0)).
        auto stepb = [&](float xb, float xe) {
            float z = B1 + xe;
            float t0v = B0 + xb;
            float d0 = t0v - z;
            float m0 = fmaxf(t0v, z);
            float u = ex2(-fabsf(d0));
            float h = fmaf(u, P2C, P1C);
            h = fmaf(u, h, P0C);
            float B0n = fmaf(u, h, m0);            // lae2(t0v, z)
            float y = skip1 ? B0n : t0v;
            float arg = shl1(y);
            float d1 = z - arg;
            float m1 = fmaxf(z, arg);
            float v = ex2(-fabsf(d1));
            float h1 = fmaf(v, P2C, P1C);
            h1 = fmaf(v, h1, P0C);
            float B1n = fmaf(v, h1, m1);           // lae2(z, arg)
            B0 = B0n; B1 = B1n;
        };
        if (K >= 35) {
            float4 S0, S1, S2, S3, S4, S5, S6, S7;
            ldG(0, S0); ldG(1, S1); ldG(2, S2); ldG(3, S3);
            ldG(4, S4); ldG(5, S5); ldG(6, S6); ldG(7, S7);
            FENCE_;
#define SUBF_B(S, G) do {                                                      \
            float e0_ = S.x * LOG2E_, e1_ = S.y * LOG2E_;                      \
            float e2_ = S.z * LOG2E_, e3_ = S.w * LOG2E_;                      \
            float b0_ = rlane(e0_, 63), b1_ = rlane(e1_, 63);                  \
            float b2_ = rlane(e2_, 63), b3_ = rlane(e3_, 63);                  \
            stepb(b0_, e0_); stepb(b1_, e1_); stepb(b2_, e2_); stepb(b3_, e3_);\
            ldG((G) + 8, S);                                                   \
            FENCE_;                                                            \
        } while (0)
            SUBF_B(S0, 0); SUBF_B(S1, 1); SUBF_B(S2, 2); SUBF_B(S3, 3);
            SUBF_B(S4, 4); SUBF_B(S5, 5); SUBF_B(S6, 6); SUBF_B(S7, 7);
            int c = 1;
            for (; 32 * c + 31 <= K - 1; ++c) {
                int g0 = 8 * c;
                SUBF_B(S0, g0 + 0); SUBF_B(S1, g0 + 1); SUBF_B(S2, g0 + 2); SUBF_B(S3, g0 + 3);
                SUBF_B(S4, g0 + 4); SUBF_B(S5, g0 + 5); SUBF_B(S6, g0 + 6); SUBF_B(S7, g0 + 7);
            }
#undef SUBF_B
            int kb = 32 * c;
#define SUBT_B(S, K0) do {                                                     \
            float e0_ = S.x * LOG2E_, e1_ = S.y * LOG2E_;                      \
            float e2_ = S.z * LOG2E_, e3_ = S.w * LOG2E_;                      \
            float b0_ = rlane(e0_, 63), b1_ = rlane(e1_, 63);                  \
            float b2_ = rlane(e2_, 63), b3_ = rlane(e3_, 63);                  \
            if ((K0) + 0 <= K - 1) stepb(b0_, e0_);                            \
            if ((K0) + 1 <= K - 1) stepb(b1_, e1_);                            \
            if ((K0) + 2 <= K - 1) stepb(b2_, e2_);                            \
            if ((K0) + 3 <= K - 1) stepb(b3_, e3_);                            \
        } while (0)
            SUBT_B(S0, kb + 0);  SUBT_B(S1, kb + 4);  SUBT_B(S2, kb + 8);  SUBT_B(S3, kb + 12);
            SUBT_B(S4, kb + 16); SUBT_B(S5, kb + 20); SUBT_B(S6, kb + 24); SUBT_B(S7, kb + 28);
#undef SUBT_B
        } else {
            for (int k = 0; k < K; ++k) {
                int t = Te - k;
                float xe = (lp + ((size_t)t << 16))[idx] * LOG2E_;
                stepb(rlane(xe, 63), xe);
            }
        }
        awb[128 + lane] = B0;
        awb[192 + lane] = B1;
    }
}

// Per-sample junction combine: fin = lae over 128 states of (alpha_M + beta_M).
__global__ __launch_bounds__(64) void combine_k(const float* __restrict__ aw,
                                                const int* __restrict__ tlen,
                                                const int* __restrict__ ilen,
                                                float* __restrict__ losses) {
    int b = blockIdx.x, lane = threadIdx.x;
    const float* awb = aw + b * 256;
    float s0 = awb[lane] + awb[128 + lane];
    float s1 = awb[64 + lane] + awb[192 + lane];
    float m = fmaxf(s0, s1);
    for (int off = 32; off; off >>= 1) m = fmaxf(m, __shfl_xor(m, off));
    float sum = ex2(s0 - m) + ex2(s1 - m);
    for (int off = 32; off; off >>= 1) sum += __shfl_xor(sum, off);
    if (lane == 0) {
        int L = tlen[b];
        float fin = lg2(sum) + m;                  // log2 domain
        if (ilen[b] <= 0) fin = NEGF;
        float loss = (L > 0) ? -fin * LN2_ : 0.0f;
        if (!(loss < 1e29f)) loss = 0.0f;          // zero_infinity (NaN-safe)
        losses[b] = loss;
    }
}

// Fallback when ws too small: fully serial per-sample forward (never hit in practice).
__global__ __launch_bounds__(64) void ctc_rec_direct_k(const float* __restrict__ lp,
                                                       const int* __restrict__ targets,
                                                       const int* __restrict__ tlen,
                                                       const int* __restrict__ ilen,
                                                       float* __restrict__ losses) {
    int b = blockIdx.x, lane = threadIdx.x;
    int tg, L;
    load_tgt(targets, tlen, b, lane, tg, L);
    int Tin = ilen[b], Te = Tin - 1;
    int tgp = __shfl_up(tg, 1);
    bool skip1 = (lane >= 1) && (tg != 0) && (tg != tgp);
    bool is16 = (lane == 16), is32 = (lane == 32), is48 = (lane == 48);
    int col = (lane == 63) ? 0 : tg;
    int idx = (b << 10) + col;
    float a0 = NEGF, a1 = NEGF;
    auto shr1 = [&](float x) -> float {
        float v15 = rlane(x, 15), v31 = rlane(x, 31), v47 = rlane(x, 47);
        float bval = is16 ? v15 : (is32 ? v31 : (is48 ? v47 : NEGF));
        return __int_as_float(__builtin_amdgcn_update_dpp(
            __float_as_int(bval), __float_as_int(x), 0x111, 0xF, 0xF, false));
    };
    auto step = [&](float xb, float xe) {
        float p1m = shr1(a1);
        float d0 = a0 - p1m;
        float m0 = fmaxf(a0, p1m);
        float u = ex2(-fabsf(d0));
        float h = fmaf(u, P2C, P1C);
        h = fmaf(u, h, P0C);
        float U = fmaf(u, h, m0);
        float na0 = U + xb;
        float w = skip1 ? U : a0;
        float d1 = a1 - w;
        float m1 = fmaxf(a1, w);
        float v = ex2(-fabsf(d1));
        float h1 = fmaf(v, P2C, P1C);
        h1 = fmaf(v, h1, P0C);
        float na1 = fmaf(v, h1, m1 + xe);
        a0 = na0; a1 = na1;
    };
    if (Tin >= 1) {
        float e = lp[idx] * LOG2E_;
        a0 = (lane == 0) ? rlane(e, 63) : NEGF;
        a1 = (lane == 0 && L > 0) ? e : NEGF;
        for (int t = 1; t <= Te; ++t) {
            float xe = (lp + ((size_t)t << 16))[idx] * LOG2E_;
            step(rlane(xe, 63), xe);
        }
    }
    int lidx = (L > 0) ? (L - 1) : 0;
    float aPrev = __shfl(a1, lidx);
    float aLast = __shfl(a0, (L < 63) ? L : 63);
    float x = aLast, y = (L > 0) ? aPrev : NEGF;
    float m = fmaxf(x, y), d = fminf(x, y) - m;
    float fin = m + lg2(1.0f + ex2(d));
    if (Tin <= 0) fin = NEGF;
    if (lane == 0) {
        float loss = (L > 0) ? -fin * LN2_ : 0.0f;
        if (!(loss < 1e29f)) loss = 0.0f;
        losses[b] = loss;
    }
}

__global__ __launch_bounds__(64) void finalize_k(const float* __restrict__ losses,
                                                 const int* __restrict__ gid,
                                                 float* __restrict__ out) {
    int lane = threadIdx.x;
    float l = losses[lane];
    int g = gid[lane];
    float s = l;
    float s0 = (g == 0) ? l : 0.0f, c0 = (g == 0) ? 1.0f : 0.0f;
    float s1 = (g == 1) ? l : 0.0f, c1 = (g == 1) ? 1.0f : 0.0f;
    for (int off = 32; off; off >>= 1) {
        s  += __shfl_xor(s, off);
        s0 += __shfl_xor(s0, off);
        c0 += __shfl_xor(c0, off);
        s1 += __shfl_xor(s1, off);
        c1 += __shfl_xor(c1, off);
    }
    if (lane == 0) {
        float base = s * (1.0f / B_);
        float m0 = s0 / fmaxf(c0, 1.0f);
        float m1 = s1 / fmaxf(c1, 1.0f);
        float mean = 0.5f * (m0 + m1);
        float var = (m0 - mean) * (m0 - mean) + (m1 - mean) * (m1 - mean); // ddof=1, N=2
        out[0] = base + 0.5f * var;
        out[1] = base;
        out[2] = var;
    }
}

extern "C" void kernel_launch(void* const* d_in, const int* in_sizes, int n_in,
                              void* d_out, int out_size, void* d_ws, size_t ws_size,
                              hipStream_t stream) {
    const float* lp = (const float*)d_in[0];
    const int* targets = (const int*)d_in[1];
    const int* ilen = (const int*)d_in[2];
    const int* tlen = (const int*)d_in[3];
    const int* gid = (const int*)d_in[4];
    float* out = (float*)d_out;

    char* ws = (char*)d_ws;
    float* losses = (float*)ws;                       // 256 B
    float* aw = (float*)(ws + 1024);                  // 64*256*4 = 64 KB
    size_t need = 1024 + (size_t)B_ * 256 * 4;

    if (ws_size >= need) {
        ctc_fb_k<<<2 * B_, 64, 0, stream>>>(lp, targets, tlen, ilen, aw);
        combine_k<<<B_, 64, 0, stream>>>(aw, tlen, ilen, losses);
    } else {
        ctc_rec_direct_k<<<B_, 64, 0, stream>>>(lp, targets, tlen, ilen, losses);
    }
    finalize_k<<<1, 64, 0, stream>>>(losses, gid, out);
}